// Round 1
// baseline (92.601 us; speedup 1.0000x reference)
//
#include <hip/hip_runtime.h>

// Problem constants (from the reference):
//   B=32, S=512, H=256, T=MAX_MEL=2000, DUR_MAX=8
// Outputs concatenated in d_out: output [B,T,H] f32 (16,384,000 floats),
// then mel_len [B] stored as float values (harness reads whole buffer as f32).
constexpr int B_ = 32;
constexpr int S_ = 512;
constexpr int H_ = 256;   // 64 float4 per row
constexpr int T_ = 2000;
constexpr int TPB_CHUNK = 32;  // t-values per block in the regulate kernel

// ---------------------------------------------------------------------------
// Kernel 1: per-batch inclusive cumsum of duration (Hillis-Steele in LDS),
// writes cumsum to workspace and mel_len (as float) to the d_out tail.
// 32 blocks x 512 threads — trivially cheap (~2 us).
// ---------------------------------------------------------------------------
__global__ __launch_bounds__(S_) void cumsum_kernel(
    const int* __restrict__ dur,        // [B,S]
    const int* __restrict__ max_len_p,  // [1]
    int* __restrict__ cum,              // [B,S] workspace
    float* __restrict__ mel_len_out)    // [B] at d_out + B*T*H
{
    const int b = blockIdx.x;
    const int tid = threadIdx.x;
    __shared__ int s[S_];
    s[tid] = dur[b * S_ + tid];
    __syncthreads();
#pragma unroll
    for (int off = 1; off < S_; off <<= 1) {
        int v = (tid >= off) ? s[tid - off] : 0;
        __syncthreads();
        s[tid] += v;
        __syncthreads();
    }
    cum[b * S_ + tid] = s[tid];
    if (tid == S_ - 1) {
        int total = s[S_ - 1];
        int ml = max_len_p[0];
        mel_len_out[b] = (float)(total < ml ? total : ml);
    }
}

// ---------------------------------------------------------------------------
// Kernel 2: the gather-expand. Block = 256 threads = 4 waves.
// Each block handles one batch b and TPB_CHUNK=32 consecutive t values.
// Cumsum row staged in LDS; wave-uniform binary search (LDS broadcast reads,
// zero divergence), then 64 lanes x float4 copy one 1 KB row (coalesced).
// ---------------------------------------------------------------------------
__global__ __launch_bounds__(256) void regulate_kernel(
    const float* __restrict__ x,   // [B,S,H]
    const int* __restrict__ cum,   // [B,S]
    float* __restrict__ out)       // [B,T,H]
{
    const int b = blockIdx.y;
    const int tid = threadIdx.x;
    const int wave = tid >> 6;
    const int lane = tid & 63;

    __shared__ int s_cum[S_];
    s_cum[tid] = cum[b * S_ + tid];
    s_cum[tid + 256] = cum[b * S_ + tid + 256];
    __syncthreads();

    const float4* __restrict__ x_b = (const float4*)(x + (size_t)b * S_ * H_);
    float4* __restrict__ out_b = (float4*)(out + (size_t)b * T_ * H_);

    const int t0 = blockIdx.x * TPB_CHUNK;
#pragma unroll
    for (int i = 0; i < TPB_CHUNK / 4; ++i) {
        const int t = t0 + i * 4 + wave;   // wave-uniform
        if (t < T_) {
            // upper_bound: first j with cum[j] > t  (== searchsorted side='right')
            int lo = 0, hi = S_;
            while (lo < hi) {
                int mid = (lo + hi) >> 1;
                if (s_cum[mid] <= t) lo = mid + 1;
                else hi = mid;
            }
            const int idx = lo < (S_ - 1) ? lo : (S_ - 1);
            out_b[(size_t)t * (H_ / 4) + lane] = x_b[(size_t)idx * (H_ / 4) + lane];
        }
    }
}

extern "C" void kernel_launch(void* const* d_in, const int* in_sizes, int n_in,
                              void* d_out, int out_size, void* d_ws, size_t ws_size,
                              hipStream_t stream) {
    const float* x = (const float*)d_in[0];
    const int* duration = (const int*)d_in[1];
    const int* max_len_p = (const int*)d_in[2];

    float* out = (float*)d_out;                          // [B,T,H]
    float* mel_len_out = out + (size_t)B_ * T_ * H_;     // [B] as floats
    int* cum = (int*)d_ws;                               // needs B*S*4 = 64 KB

    cumsum_kernel<<<B_, S_, 0, stream>>>(duration, max_len_p, cum, mel_len_out);

    dim3 grid((T_ + TPB_CHUNK - 1) / TPB_CHUNK, B_);     // 63 x 32 = 2016 blocks
    regulate_kernel<<<grid, 256, 0, stream>>>(x, cum, out);
}

// Round 3
// 91.211 us; speedup vs baseline: 1.0152x; 1.0152x over previous
//
#include <hip/hip_runtime.h>

// Problem constants (from the reference):
//   B=32, S=512, H=256, T=MAX_MEL=2000, DUR_MAX=8
// d_out layout: output [B,T,H] f32 (16,384,000 floats), then mel_len [B]
// stored as float values.
constexpr int B_ = 32;
constexpr int S_ = 512;
constexpr int H_ = 256;          // 64 float4 per row
constexpr int T_ = 2000;
constexpr int F4_PER_ROW = H_ / 4;   // 64

// Native vector type — __builtin_nontemporal_store rejects HIP_vector_type.
typedef float f32x4 __attribute__((ext_vector_type(4)));

// ---------------------------------------------------------------------------
// Kernel 1: per-batch scan of duration -> scatter the inverse map idx[B,T].
// idx[b][t] = searchsorted(cumsum(dur[b]), t, 'right') clipped to S-1.
// Thread s owns rows [cum[s-1], cum[s]) -> writes s (at most DUR_MAX=8 ints).
// Tail [total, T) gets S-1. 32 blocks x 512 threads — a few us.
// ---------------------------------------------------------------------------
__global__ __launch_bounds__(S_) void build_idx_kernel(
    const int* __restrict__ dur,        // [B,S]
    const int* __restrict__ max_len_p,  // [1]
    int* __restrict__ idx,              // [B,T] workspace
    float* __restrict__ mel_len_out)    // [B] at d_out + B*T*H
{
    const int b = blockIdx.x;
    const int tid = threadIdx.x;
    __shared__ int s[S_];
    s[tid] = dur[b * S_ + tid];
    __syncthreads();
#pragma unroll
    for (int off = 1; off < S_; off <<= 1) {
        int v = (tid >= off) ? s[tid - off] : 0;
        __syncthreads();
        s[tid] += v;
        __syncthreads();
    }
    const int hi = s[tid];                       // cum[tid]
    const int lo = tid ? s[tid - 1] : 0;         // cum[tid-1]
    const int total = s[S_ - 1];

    int* __restrict__ idx_b = idx + b * T_;
    const int hic = hi < T_ ? hi : T_;
    for (int t = lo; t < hic; ++t) idx_b[t] = tid;          // scatter inverse map
    for (int t = total + tid; t < T_; t += S_) idx_b[t] = S_ - 1;  // tail

    if (tid == 0) {
        const int ml = max_len_p[0];
        mel_len_out[b] = (float)(total < ml ? total : ml);
    }
}

// ---------------------------------------------------------------------------
// Kernel 2: pure streaming gather. One float4 per thread; block = 256 threads
// = 4 t-rows (64 lanes x float4 = one 1 KB row each). XCD-aware swizzle pins
// each batch's blocks to one XCD (4 batches x 512 KB = 2 MB of x per XCD L2);
// non-temporal stores keep the 65 MB output stream from evicting x.
// Grid: 32 batches x 500 blocks = 16000 blocks.
// ---------------------------------------------------------------------------
constexpr int BLOCKS_PER_B = (T_ * F4_PER_ROW) / 256;  // 500
constexpr int NUM_XCD = 8;

__global__ __launch_bounds__(256) void gather_kernel(
    const f32x4* __restrict__ x,     // [B,S,64]
    const int* __restrict__ idx,     // [B,T]
    f32x4* __restrict__ out)         // [B,T,64]
{
    const int id = blockIdx.x;               // 0..15999
    const int xcd = id & (NUM_XCD - 1);      // target XCD under round-robin dispatch
    const int j = id >> 3;                   // 0..1999
    const int b = xcd + NUM_XCD * (j / BLOCKS_PER_B);  // 4 batches per XCD
    const int chunk = j % BLOCKS_PER_B;

    const int t = chunk * 4 + (threadIdx.x >> 6);
    const int lane = threadIdx.x & 63;

    const int s = idx[b * T_ + t];           // wave-uniform broadcast load (L2-hot)
    const f32x4 v = x[((size_t)b * S_ + s) * F4_PER_ROW + lane];
    __builtin_nontemporal_store(v, &out[((size_t)b * T_ + t) * F4_PER_ROW + lane]);
}

extern "C" void kernel_launch(void* const* d_in, const int* in_sizes, int n_in,
                              void* d_out, int out_size, void* d_ws, size_t ws_size,
                              hipStream_t stream) {
    const float* x = (const float*)d_in[0];
    const int* duration = (const int*)d_in[1];
    const int* max_len_p = (const int*)d_in[2];

    float* out = (float*)d_out;                        // [B,T,H]
    float* mel_len_out = out + (size_t)B_ * T_ * H_;   // [B] as floats
    int* idx = (int*)d_ws;                             // B*T*4 = 256 KB

    build_idx_kernel<<<B_, S_, 0, stream>>>(duration, max_len_p, idx, mel_len_out);

    gather_kernel<<<B_ * BLOCKS_PER_B, 256, 0, stream>>>(
        (const f32x4*)x, idx, (f32x4*)out);
}

// Round 4
// 87.964 us; speedup vs baseline: 1.0527x; 1.0369x over previous
//
#include <hip/hip_runtime.h>

// B=32, S=512, H=256, T=MAX_MEL=2000, DUR_MAX=8
// d_out: output [B,T,H] f32 (16,384,000 floats) then mel_len [B] as floats.
//
// SINGLE fused dispatch. Each block:
//   1. loads its batch's 512 durations (2/thread, int2),
//   2. shuffle-scan (6-step wave scan + 4-wave LDS combine) -> cumsum in LDS,
//   3. each wave: wave-uniform binary search (LDS broadcast, no divergence)
//      for its t row, then 64 lanes x float4 coalesced row copy, nt stores.
// No workspace, no second kernel, no inter-dispatch dependency.
constexpr int B_ = 32;
constexpr int S_ = 512;
constexpr int H_ = 256;
constexpr int T_ = 2000;
constexpr int F4 = H_ / 4;                 // 64 float4 per row
constexpr int ROWS_PER_BLOCK = 32;         // t-rows per block (4 waves x 8 iters)
constexpr int NBLK_T = (T_ + ROWS_PER_BLOCK - 1) / ROWS_PER_BLOCK;  // 63

typedef float f32x4 __attribute__((ext_vector_type(4)));

__global__ __launch_bounds__(256) void lenreg_fused_kernel(
    const f32x4* __restrict__ x,        // [B,S,64]
    const int* __restrict__ dur,        // [B,S]
    const int* __restrict__ max_len_p,  // [1]
    f32x4* __restrict__ out,            // [B,T,64]
    float* __restrict__ mel_len_out)    // [B]
{
    const int b = blockIdx.y;
    const int tid = threadIdx.x;
    const int lane = tid & 63;
    const int wave = tid >> 6;

    __shared__ int s_cum[S_];
    __shared__ int s_wsum[4];

    // --- cumsum of dur[b][:] : 2 elements per thread ---
    const int2 d2 = ((const int2*)(dur + b * S_))[tid];
    const int pair = d2.x + d2.y;
    int scan = pair;                       // inclusive wave scan of pair sums
#pragma unroll
    for (int off = 1; off < 64; off <<= 1) {
        const int y = __shfl_up(scan, off);
        if (lane >= off) scan += y;
    }
    if (lane == 63) s_wsum[wave] = scan;
    __syncthreads();
    int wprefix = 0;
#pragma unroll
    for (int w = 0; w < 4; ++w) wprefix += (w < wave) ? s_wsum[w] : 0;
    const int excl = wprefix + scan - pair;   // exclusive prefix of element 2*tid
    s_cum[2 * tid]     = excl + d2.x;
    s_cum[2 * tid + 1] = excl + pair;
    __syncthreads();

    if (blockIdx.x == 0 && tid == 0) {
        const int total = s_cum[S_ - 1];
        const int ml = max_len_p[0];
        mel_len_out[b] = (float)(total < ml ? total : ml);
    }

    const f32x4* __restrict__ x_b = x + (size_t)b * S_ * F4;
    f32x4* __restrict__ out_b = out + (size_t)b * T_ * F4;

    const int t0 = blockIdx.x * ROWS_PER_BLOCK;
#pragma unroll
    for (int i = 0; i < ROWS_PER_BLOCK / 4; ++i) {
        const int t = t0 + i * 4 + wave;     // wave-uniform
        if (t < T_) {
            // upper_bound: first j with cum[j] > t; 9 fixed steps for S=512
            int lo = 0, hi = S_;
#pragma unroll
            for (int step = 0; step < 9; ++step) {
                const int mid = (lo + hi) >> 1;
                if (s_cum[mid] <= t) lo = mid + 1; else hi = mid;
            }
            const int idx = lo < (S_ - 1) ? lo : (S_ - 1);
            const f32x4 v = x_b[(size_t)idx * F4 + lane];
            __builtin_nontemporal_store(v, &out_b[(size_t)t * F4 + lane]);
        }
    }
}

extern "C" void kernel_launch(void* const* d_in, const int* in_sizes, int n_in,
                              void* d_out, int out_size, void* d_ws, size_t ws_size,
                              hipStream_t stream) {
    const f32x4* x = (const f32x4*)d_in[0];
    const int* duration = (const int*)d_in[1];
    const int* max_len_p = (const int*)d_in[2];

    float* out = (float*)d_out;                        // [B,T,H]
    float* mel_len_out = out + (size_t)B_ * T_ * H_;   // [B] as floats

    dim3 grid(NBLK_T, B_);                             // 63 x 32 = 2016 blocks
    lenreg_fused_kernel<<<grid, 256, 0, stream>>>(
        x, duration, max_len_p, (f32x4*)out, mel_len_out);
}